// Round 2
// baseline (223.126 us; speedup 1.0000x reference)
//
#include <hip/hip_runtime.h>

#define STEPS 10
#define NN 6

__global__ __launch_bounds__(256) void spiking_vestibular_kernel(
    const float* __restrict__ speed,
    const float* __restrict__ turn_rate,
    const float* __restrict__ predicted_turn,
    const float* __restrict__ predicted_speed,
    const float* __restrict__ noise,
    const float* __restrict__ v0,
    const float* __restrict__ u0,
    const float* __restrict__ rate0,
    float* __restrict__ out,
    int B)
{
#pragma clang fp contract(off)
    int b = blockIdx.x * blockDim.x + threadIdx.x;
    if (b >= B) return;

    size_t base6 = (size_t)b * NN;

    // ---- Issue ALL global loads up front: 30x float2 of noise + state ----
    float2 nz2[STEPS][3];
#pragma unroll
    for (int t = 0; t < STEPS; ++t) {
        const float2* p = reinterpret_cast<const float2*>(
            noise + ((size_t)t * (size_t)B) * NN + base6);
        nz2[t][0] = p[0];
        nz2[t][1] = p[1];
        nz2[t][2] = p[2];
    }

    float v[NN], u[NN], r[NN];
    {
        const float2* p = reinterpret_cast<const float2*>(v0 + base6);
        float2 a0 = p[0], a1 = p[1], a2 = p[2];
        v[0] = a0.x; v[1] = a0.y; v[2] = a1.x; v[3] = a1.y; v[4] = a2.x; v[5] = a2.y;
    }
    {
        const float2* p = reinterpret_cast<const float2*>(u0 + base6);
        float2 a0 = p[0], a1 = p[1], a2 = p[2];
        u[0] = a0.x; u[1] = a0.y; u[2] = a1.x; u[3] = a1.y; u[4] = a2.x; u[5] = a2.y;
    }
    {
        const float2* p = reinterpret_cast<const float2*>(rate0 + base6);
        float2 a0 = p[0], a1 = p[1], a2 = p[2];
        r[0] = a0.x; r[1] = a0.y; r[2] = a1.x; r[3] = a1.y; r[4] = a2.x; r[5] = a2.y;
    }

    float tr = turn_rate[b];
    float sp = speed[b];
    float pt = predicted_turn[b];
    float ps = predicted_speed[b];

    float tilt = fminf(1.0f, fabsf(tr) * sp * 0.5f);

    float I[NN];
    I[0] = fmaxf(0.0f, tr) * 10.0f;
    I[1] = fmaxf(0.0f, -tr) * 10.0f;
    I[2] = sp * 5.0f;
    I[3] = fmaxf(0.0f, -sp + 0.5f) * 5.0f;
    I[4] = tilt * 8.0f;
    I[5] = tilt * 8.0f;

    // ---- Izhikevich recurrence, fully unrolled ----
#pragma unroll
    for (int t = 0; t < STEPS; ++t) {
        float nz[NN] = { nz2[t][0].x, nz2[t][0].y,
                         nz2[t][1].x, nz2[t][1].y,
                         nz2[t][2].x, nz2[t][2].y };
#pragma unroll
        for (int n = 0; n < NN; ++n) {
            // i_tot = I + nz*NOISE_STD + I_TONIC  (left-to-right)
            float i_tot = I[n] + nz[n] * 0.3f + (-1.0f);
            float vv = v[n];
            float un = u[n];
            // v = v + (0.04*v*v + 5.0*v + 140.0 - u + i_tot)
            vv = vv + (((((0.04f * vv) * vv) + (5.0f * vv)) + 140.0f) - un + i_tot);
            // u = u + a*(b*v - u)
            un = un + 0.02f * ((0.2f * vv) - un);
            bool fired = (vv >= 30.0f);
            float spk = fired ? 1.0f : 0.0f;
            vv = fired ? -65.0f : vv;
            un = un + spk * 8.0f;
            r[n] = r[n] * 0.9f + spk * 0.1f;
            v[n] = vv;
            u[n] = un;
        }
    }

    float rsum = ((((r[0] + r[1]) + r[2]) + r[3]) + r[4]) + r[5];
    float rate_mean = rsum / 6.0f;

    // ---- TwoCompColumn relaxation: 8 substeps, vb/va start at 0 ----
    float vb0 = 0.0f, vb1 = 0.0f, va0 = 0.0f, va1 = 0.0f;
#pragma unroll
    for (int k = 0; k < 8; ++k) {
        vb0 = vb0 + 0.5f * (tr - vb0);
        vb1 = vb1 + 0.5f * (sp - vb1);
        va0 = va0 + 0.5f * (pt - va0);
        va1 = va1 + 0.5f * (ps - va1);
    }
    float pe0 = vb0 - va0;
    float pe1 = vb1 - va1;
    float prec0 = 1.0f / (1.0f + pe0 * pe0);
    float prec1 = 1.0f / (1.0f + pe1 * pe1);
    float fe = 0.5f * (((prec0 * pe0) * pe0) + ((prec1 * pe1) * pe1));
    float pe_w = 0.7f * pe0 + 0.3f * pe1;
    float prec_mean = (prec0 + prec1) / 2.0f;
    float postural = (-prec_mean) * pe_w * 0.3f;

    float2* o = reinterpret_cast<float2*>(out + base6);
    o[0] = make_float2(tilt, rate_mean);
    o[1] = make_float2(postural, pe_w);
    o[2] = make_float2(prec_mean, fe);
}

extern "C" void kernel_launch(void* const* d_in, const int* in_sizes, int n_in,
                              void* d_out, int out_size, void* d_ws, size_t ws_size,
                              hipStream_t stream) {
    // setup_inputs order:
    // 0 heading (unused), 1 speed, 2 turn_rate, 3 predicted_turn,
    // 4 predicted_speed, 5 noise [STEPS,B,N], 6 v0, 7 u0, 8 rate0
    const float* speed           = (const float*)d_in[1];
    const float* turn_rate       = (const float*)d_in[2];
    const float* predicted_turn  = (const float*)d_in[3];
    const float* predicted_speed = (const float*)d_in[4];
    const float* noise           = (const float*)d_in[5];
    const float* v0              = (const float*)d_in[6];
    const float* u0              = (const float*)d_in[7];
    const float* rate0           = (const float*)d_in[8];
    float* out                   = (float*)d_out;

    int B = in_sizes[1];
    int block = 256;
    int grid = (B + block - 1) / block;
    spiking_vestibular_kernel<<<grid, block, 0, stream>>>(
        speed, turn_rate, predicted_turn, predicted_speed,
        noise, v0, u0, rate0, out, B);
}

// Round 3
// 219.154 us; speedup vs baseline: 1.0181x; 1.0181x over previous
//
#include <hip/hip_runtime.h>

#define STEPS 10

// 4 lanes per batch element: lane g in {0,1,2} owns neurons {2g, 2g+1};
// lane g==3 is a passenger (clamped loads, no store) so shuffles stay defined.
__global__ __launch_bounds__(256) void spiking_vestibular_kernel(
    const float* __restrict__ speed,
    const float* __restrict__ turn_rate,
    const float* __restrict__ predicted_turn,
    const float* __restrict__ predicted_speed,
    const float* __restrict__ noise,
    const float* __restrict__ v0,
    const float* __restrict__ u0,
    const float* __restrict__ rate0,
    float* __restrict__ out,
    int B)
{
#pragma clang fp contract(off)
    int tid = blockIdx.x * blockDim.x + threadIdx.x;
    int b = tid >> 2;
    int g = tid & 3;
    if (b >= B) return;

    size_t base6 = (size_t)b * 6;
    int goff = (g == 3) ? 0 : (2 * g);   // lane 3: duplicate lane 0's (in-bounds)

    // ---- hoist ALL per-thread global loads (10 noise float2, independent) ----
    float2 nz[STEPS];
#pragma unroll
    for (int t = 0; t < STEPS; ++t)
        nz[t] = *reinterpret_cast<const float2*>(noise + (size_t)t * (size_t)B * 6 + base6 + goff);

    float2 v2 = *reinterpret_cast<const float2*>(v0    + base6 + goff);
    float2 u2 = *reinterpret_cast<const float2*>(u0    + base6 + goff);
    float2 r2 = *reinterpret_cast<const float2*>(rate0 + base6 + goff);

    float tr = turn_rate[b];
    float sp = speed[b];
    float pt = predicted_turn[b];
    float ps = predicted_speed[b];

    float tilt = fminf(1.0f, (fabsf(tr) * sp) * 0.5f);

    // Per-lane drive currents for its two neurons.
    float t8 = tilt * 8.0f;
    float Ia = (g == 0) ? fmaxf(0.0f, tr) * 10.0f
             : (g == 1) ? sp * 5.0f
             : t8;
    float Ib = (g == 0) ? fmaxf(0.0f, -tr) * 10.0f
             : (g == 1) ? fmaxf(0.0f, -sp + 0.5f) * 5.0f
             : t8;

    float va = v2.x, vb = v2.y;
    float ua = u2.x, ub = u2.y;
    float ra = r2.x, rb = r2.y;

#pragma unroll
    for (int t = 0; t < STEPS; ++t) {
        {   // neuron A = 2g
            float i_tot = Ia + nz[t].x * 0.3f + (-1.0f);
            float vv = va, un = ua;
            vv = vv + (((((0.04f * vv) * vv) + (5.0f * vv)) + 140.0f) - un + i_tot);
            un = un + 0.02f * ((0.2f * vv) - un);
            bool fired = (vv >= 30.0f);
            float spk = fired ? 1.0f : 0.0f;
            vv = fired ? -65.0f : vv;
            un = un + spk * 8.0f;
            ra = ra * 0.9f + spk * 0.1f;
            va = vv; ua = un;
        }
        {   // neuron B = 2g+1
            float i_tot = Ib + nz[t].y * 0.3f + (-1.0f);
            float vv = vb, un = ub;
            vv = vv + (((((0.04f * vv) * vv) + (5.0f * vv)) + 140.0f) - un + i_tot);
            un = un + 0.02f * ((0.2f * vv) - un);
            bool fired = (vv >= 30.0f);
            float spk = fired ? 1.0f : 0.0f;
            vv = fired ? -65.0f : vv;
            un = un + spk * 8.0f;
            rb = rb * 0.9f + spk * 0.1f;
            vb = vv; ub = un;
        }
    }

    // rate_mean: sum over the group's 3 active lanes (needed on lane 0 only)
    float s  = ra + rb;
    float s1 = __shfl_down(s, 1, 4);
    float s2 = __shfl_down(s, 2, 4);
    float rate_mean = ((s + s1) + s2) / 6.0f;

    // ---- TwoCompColumn relaxation (redundant on all lanes, cheap) ----
    float cb0 = 0.0f, cb1 = 0.0f, ca0 = 0.0f, ca1 = 0.0f;
#pragma unroll
    for (int k = 0; k < 8; ++k) {
        cb0 = cb0 + 0.5f * (tr - cb0);
        cb1 = cb1 + 0.5f * (sp - cb1);
        ca0 = ca0 + 0.5f * (pt - ca0);
        ca1 = ca1 + 0.5f * (ps - ca1);
    }
    float pe0 = cb0 - ca0;
    float pe1 = cb1 - ca1;
    float prec0 = 1.0f / (1.0f + pe0 * pe0);
    float prec1 = 1.0f / (1.0f + pe1 * pe1);
    float fe = 0.5f * (((prec0 * pe0) * pe0) + ((prec1 * pe1) * pe1));
    float pe_w = 0.7f * pe0 + 0.3f * pe1;
    float prec_mean = (prec0 + prec1) / 2.0f;
    float postural = (-prec_mean) * pe_w * 0.3f;

    if (g < 3) {
        float2 o = (g == 0) ? make_float2(tilt, rate_mean)
                 : (g == 1) ? make_float2(postural, pe_w)
                 :            make_float2(prec_mean, fe);
        *reinterpret_cast<float2*>(out + base6 + 2 * g) = o;
    }
}

extern "C" void kernel_launch(void* const* d_in, const int* in_sizes, int n_in,
                              void* d_out, int out_size, void* d_ws, size_t ws_size,
                              hipStream_t stream) {
    // setup_inputs order:
    // 0 heading (unused), 1 speed, 2 turn_rate, 3 predicted_turn,
    // 4 predicted_speed, 5 noise [STEPS,B,N], 6 v0, 7 u0, 8 rate0
    const float* speed           = (const float*)d_in[1];
    const float* turn_rate       = (const float*)d_in[2];
    const float* predicted_turn  = (const float*)d_in[3];
    const float* predicted_speed = (const float*)d_in[4];
    const float* noise           = (const float*)d_in[5];
    const float* v0              = (const float*)d_in[6];
    const float* u0              = (const float*)d_in[7];
    const float* rate0           = (const float*)d_in[8];
    float* out                   = (float*)d_out;

    int B = in_sizes[1];
    long long total = (long long)B * 4;
    int block = 256;
    int grid = (int)((total + block - 1) / block);
    spiking_vestibular_kernel<<<grid, block, 0, stream>>>(
        speed, turn_rate, predicted_turn, predicted_speed,
        noise, v0, u0, rate0, out, B);
}